// Round 3
// baseline (953.789 us; speedup 1.0000x reference)
//
#include <hip/hip_runtime.h>

// Problem constants (from reference)
#define Bdim   4
#define Tdim   1024
#define NLAB   64
#define Cdim   256
#define Ddim   512
#define HALFD  256        // VALUE_DIM/2
#define APAD   260        // padded A row pitch (floats): +4*l bank rotation per label
#define WC     16         // c columns owned per block
#define NCS    (Cdim/WC)  // 16 c-slices
#define NBLK   (Bdim*NCS) // 64 blocks

// ROUND-3 DISCRIMINATING EXPERIMENT:
// Round-2 profile showed top-5 dispatches are ALL 2 GiB fillBufferAligned
// (~333 us each, WRITE_SIZE = 2 GiB = ws poison) and vb_kernel < 331 us,
// yet dur_us 609 ~= baseline 604.9 across two structurally different
// kernels. Theory: the measured time is dominated by harness ws re-poison
// fills in the timed window ("re-poison semantics" tripwire), not kernel.
// This kernel: NO d_ws, NO hipMemsetAsync, NO global atomics, ONE launch.
// Each out[b,c] is written exactly once by one block (plain store), so no
// pre-zeroed output is needed.
//
// Decomposition: grid = b(4) x c-slice(16); block builds the FULL per-label
// accumulator A[l][d] for its b in LDS (64 labels x 256 d = 64 KB, swizzled)
// via ds_add_f32 -- no label compaction at all; label picks the LDS row.
// Stage 2 contracts A against W[l, half+d, c-slice] and stores 4x16 outputs.
__global__ __launch_bounds__(512) void vb_kernel(
    const int*   __restrict__ indices,   // [B*T]
    const float* __restrict__ scores,    // [B*T]
    const float* __restrict__ W,         // [NLAB, Ddim, Cdim]
    const int*   __restrict__ label,     // [B*T]
    const int*   __restrict__ index_p,   // [1]
    const float* __restrict__ weight,    // [VALUE_SIZE, Ddim]
    float*       __restrict__ out)       // [B, Cdim]
{
    const int b    = blockIdx.x >> 4;        // 0..3
    const int cs   = blockIdx.x & 15;        // 0..15
    const int tid  = threadIdx.x;
    const int half = (index_p[0] == 1) ? HALFD : 0;
    const int c0   = cs * WC;

    __shared__ float A[NLAB][APAD];          // 66,560 B : A[l][col(d)]
    __shared__ int   s_idx[Tdim];            // 4 KB
    __shared__ float s_sc [Tdim];            // 4 KB
    __shared__ int   s_lb [Tdim];            // 4 KB
    __shared__ float P2[32][WC + 1];         // 2.2 KB (dq-partials, padded)

    // ---- zero A + stage (idx, score, label) triplets for our b ----
    for (int i = tid; i < NLAB * APAD; i += 512) (&A[0][0])[i] = 0.0f;
    for (int t = tid; t < Tdim; t += 512) {
        s_idx[t] = indices[b * Tdim + t];
        s_sc [t] = scores [b * Tdim + t];
        s_lb [t] = label  [b * Tdim + t];
    }
    __syncthreads();

    // ---- stage 1: A[label[t]][col(d)] += score[t] * weight[idx[t], half+d] ----
    // 32 slots x 16 lanes; slot handles rows t = it*32+slot; lane cl covers
    // d = cl*4 + 64k + j (4 float4 loads, each wave-instruction a contiguous
    // 256 B segment -> perfectly coalesced).
    const int slot = tid >> 4;               // 0..31
    const int cl   = tid & 15;               // 0..15

    // Lane-invariant swizzled float-offsets (static indices only -> registers).
    // col(16m + r) = 16m | ((r+m)&15): bijective per 16-group, spreads the
    // stride-4 ds_add pattern across all 32 banks (unswizzled = 8-way conflict).
    int colo[16];
    #pragma unroll
    for (int k = 0; k < 4; ++k) {
        #pragma unroll
        for (int j = 0; j < 4; ++j) {
            int dj  = cl * 4 + j;                      // < 64
            int m   = (dj >> 4) + 4 * k;
            int col = (m << 4) | (((dj & 15) + m) & 15);
            colo[k * 4 + j] = col;
        }
    }

    #pragma unroll 2
    for (int it = 0; it < Tdim / 32; ++it) {
        int   t   = it * 32 + slot;
        int   idx = s_idx[t];
        float s   = s_sc [t];
        int   l   = s_lb [t];
        const float* wrow = weight + (size_t)idx * Ddim + half + cl * 4;
        float4 w0 = *(const float4*)(wrow);
        float4 w1 = *(const float4*)(wrow + 64);
        float4 w2 = *(const float4*)(wrow + 128);
        float4 w3 = *(const float4*)(wrow + 192);
        float* Arow = &A[l][0];
        atomicAdd(Arow + colo[ 0], s * w0.x); atomicAdd(Arow + colo[ 1], s * w0.y);
        atomicAdd(Arow + colo[ 2], s * w0.z); atomicAdd(Arow + colo[ 3], s * w0.w);
        atomicAdd(Arow + colo[ 4], s * w1.x); atomicAdd(Arow + colo[ 5], s * w1.y);
        atomicAdd(Arow + colo[ 6], s * w1.z); atomicAdd(Arow + colo[ 7], s * w1.w);
        atomicAdd(Arow + colo[ 8], s * w2.x); atomicAdd(Arow + colo[ 9], s * w2.y);
        atomicAdd(Arow + colo[10], s * w2.z); atomicAdd(Arow + colo[11], s * w2.w);
        atomicAdd(Arow + colo[12], s * w3.x); atomicAdd(Arow + colo[13], s * w3.y);
        atomicAdd(Arow + colo[14], s * w3.z); atomicAdd(Arow + colo[15], s * w3.w);
    }
    __syncthreads();

    // ---- stage 2: acc(c_loc,dq) = sum_l sum_k A[l][col(dq+32k)] * W[l, half+dq+32k, c0+c_loc] ----
    // LDS reads: 4 distinct addresses per wave (16-lane broadcast each) -> conflict-free.
    // W reads: 16 consecutive c per 16-lane group -> 64 B lines, coalesced.
    const int c_loc = tid & 15;
    const int dq    = tid >> 4;              // 0..31
    float acc = 0.0f;
    #pragma unroll 2
    for (int l = 0; l < NLAB; ++l) {
        const float* Wl = W + (((size_t)l * Ddim + half + dq) * Cdim) + c0 + c_loc;
        #pragma unroll
        for (int k = 0; k < 8; ++k) {
            int d   = dq + 32 * k;
            int m   = d >> 4;
            int col = (m << 4) | (((d & 15) + m) & 15);
            acc += A[l][col] * Wl[(size_t)(32 * k) * Cdim];
        }
    }
    P2[dq][c_loc] = acc;
    __syncthreads();

    // ---- final dq-reduce + single plain store per output element ----
    if (tid < WC) {
        float ssum = 0.0f;
        #pragma unroll
        for (int q = 0; q < 32; ++q) ssum += P2[q][tid];
        out[b * Cdim + c0 + tid] = ssum;     // exclusive owner: no atomics, no memset
    }
}

extern "C" void kernel_launch(void* const* d_in, const int* in_sizes, int n_in,
                              void* d_out, int out_size, void* d_ws, size_t ws_size,
                              hipStream_t stream) {
    const int*   indices = (const int*)  d_in[0];
    const float* scores  = (const float*)d_in[1];
    const float* W       = (const float*)d_in[2];
    const int*   label   = (const int*)  d_in[3];
    const int*   index_p = (const int*)  d_in[4];
    const float* weight  = (const float*)d_in[5];
    float*       out     = (float*)d_out;

    // Single launch; d_ws deliberately untouched (tests the re-poison theory).
    vb_kernel<<<dim3(NBLK), dim3(512), 0, stream>>>(
        indices, scores, W, label, index_p, weight, out);
}